// Round 8
// baseline (734.178 us; speedup 1.0000x reference)
//
#include <hip/hip_runtime.h>

#define TT 6
#define D 128
#define KTOT 896           // 6*128 means + 128 x-slab
#define BM 128
#define APITCH 132         // fp32 LDS A pitch: 528B row, 16B aligned, 2-way banks
#define SCAN_BLK 2048
#define LN_EPS 1e-5f

typedef __bf16 bf16x8 __attribute__((ext_vector_type(8)));
typedef float f32x4 __attribute__((ext_vector_type(4)));

__device__ __forceinline__ unsigned short f2bf(float f) {
    unsigned int u = __float_as_uint(f);
    unsigned int r = (u + 0x7FFFu + ((u >> 16) & 1u)) >> 16;  // RNE
    return (unsigned short)r;
}
__device__ __forceinline__ float bflo(unsigned int v) { return __uint_as_float(v << 16); }
__device__ __forceinline__ float bfhi(unsigned int v) { return __uint_as_float(v & 0xffff0000u); }
// pack 2 fp32 -> 2 bf16 (round-half-up; cheap, error ≪ threshold)
__device__ __forceinline__ unsigned int pkbf(float f0, float f1) {
    unsigned int u0 = (__float_as_uint(f0) + 0x8000u) >> 16;
    unsigned int u1 = (__float_as_uint(f1) + 0x8000u) & 0xffff0000u;
    return u0 | u1;
}

// --- setup: cast x->xb, transpose weights to bf16 WlT, bias_total, zero hist+flags ---
__global__ void setup_kernel(const float* __restrict__ x, const float* __restrict__ W_l,
                             const float* __restrict__ W_r, const float* __restrict__ b,
                             const float* __restrict__ emb,
                             unsigned short* __restrict__ xb, unsigned short* __restrict__ WlT,
                             float* __restrict__ bias_total, int* __restrict__ hist,
                             int* __restrict__ flag, int total8, int S, int NB) {
    int i = blockIdx.x * 256 + threadIdx.x;
    if (i < total8) {
        const float4* p = (const float4*)x + (size_t)i * 2;
        float4 a = p[0], bb = p[1];
        uint4 o;
        o.x = (unsigned int)f2bf(a.x) | ((unsigned int)f2bf(a.y) << 16);
        o.y = (unsigned int)f2bf(a.z) | ((unsigned int)f2bf(a.w) << 16);
        o.z = (unsigned int)f2bf(bb.x) | ((unsigned int)f2bf(bb.y) << 16);
        o.w = (unsigned int)f2bf(bb.z) | ((unsigned int)f2bf(bb.w) << 16);
        ((uint4*)xb)[i] = o;
        return;
    }
    i -= total8;
    if (i < 6 * D * D) {
        int t = i >> 14, rem = i & 16383, k = rem >> 7, n = rem & 127;
        WlT[n * KTOT + t * D + k] = f2bf(W_l[i]);
        return;
    }
    if (i < 7 * D * D) {
        int rem = i & 16383, k = rem >> 7, n = rem & 127;
        float s = 0.f;
#pragma unroll
        for (int tt = 0; tt < TT; ++tt) s += W_r[tt * D * D + rem];
        WlT[n * KTOT + TT * D + k] = f2bf(s);
        return;
    }
    if (i < 7 * D * D + D) {
        int o = i - 7 * D * D;
        float s = 0.f;
#pragma unroll
        for (int t = 0; t < TT; ++t) s += b[t * D + o] + emb[t * D + o];
        bias_total[o] = s;
        return;
    }
    i -= 7 * D * D + D;
    if (i < S) { hist[i] = 0; return; }
    i -= S;
    if (i < NB) flag[i] = 0;
}

// --- histogram of seg = t*N + dst (slab-contiguous CSR) ---
__global__ void hist_kernel(const int* __restrict__ ei, const int* __restrict__ et,
                            int* __restrict__ hist, int E, int N) {
    int e = blockIdx.x * 256 + threadIdx.x;
    if (e >= E) return;
    atomicAdd(&hist[et[e] * N + ei[E + e]], 1);
}

// --- single-dispatch exclusive scan (decoupled lookback, all-aggregate form) ---
__global__ void scan_kernel(const int* __restrict__ in, int* __restrict__ off,
                            int* __restrict__ cursor, int* __restrict__ agg,
                            int* __restrict__ flag, int S, int E) {
    __shared__ int wsum[4];
    __shared__ int woff[4];
    __shared__ int psum[4];
    __shared__ int s_prefix;
    int tid = threadIdx.x;
    int tile = blockIdx.x;
    int base = tile * SCAN_BLK + tid * 8;
    int v[8];
    int ts = 0;
#pragma unroll
    for (int j = 0; j < 8; ++j) {
        v[j] = (base + j < S) ? in[base + j] : 0;
        ts += v[j];
    }
    int lane = tid & 63, wave = tid >> 6;
    int inc = ts;
#pragma unroll
    for (int o = 1; o < 64; o <<= 1) {
        int n = __shfl_up(inc, o);
        if (lane >= o) inc += n;
    }
    if (lane == 63) wsum[wave] = inc;
    __syncthreads();
    if (tid == 0) {
        int r = 0;
#pragma unroll
        for (int w = 0; w < 4; ++w) { int t = wsum[w]; woff[w] = r; r += t; }
        agg[tile] = r;
        __threadfence();
        atomicExch(&flag[tile], 1);
    }
    int part = 0;
    for (int j = tid; j < tile; j += 256) {
        while (atomicAdd(&flag[j], 0) == 0) {}
        part += atomicAdd(&agg[j], 0);
    }
#pragma unroll
    for (int o = 32; o >= 1; o >>= 1) part += __shfl_down(part, o);
    if (lane == 0) psum[wave] = part;
    __syncthreads();
    if (tid == 0) s_prefix = psum[0] + psum[1] + psum[2] + psum[3];
    __syncthreads();
    int run = s_prefix + woff[wave] + inc - ts;
#pragma unroll
    for (int j = 0; j < 8; ++j) {
        if (base + j < S) { off[base + j] = run; cursor[base + j] = run; }
        run += v[j];
    }
    if (tile == 0 && tid == 0) off[S] = E;
}

// --- fill: edge -> segment-sorted packed (src | local_row<<17).  N<2^17, row<2^7.
__global__ void fill_kernel(const int* __restrict__ ei, const int* __restrict__ et,
                            int* __restrict__ cursor, int* __restrict__ spk,
                            int E, int N) {
    int e = blockIdx.x * 256 + threadIdx.x;
    if (e >= E) return;
    int dst = ei[E + e];
    int seg = et[e] * N + dst;
    int pos = atomicAdd(&cursor[seg], 1);
    spk[pos] = ei[e] | ((dst & (BM - 1)) << 17);
}

// --- fused: edge-parallel LDS-atomic mean aggregation -> bf16 MFMA -> bias+LN+ReLU ---
__launch_bounds__(256, 2)
__global__ void fused_kernel(const unsigned short* __restrict__ xb,
                             const int* __restrict__ off, const int* __restrict__ spk,
                             const unsigned short* __restrict__ WlT,
                             const float* __restrict__ bias_total,
                             const float* __restrict__ gamma, const float* __restrict__ beta,
                             float* __restrict__ out, int N) {
    __shared__ float Asf[BM * APITCH];        // 66 KB fp32 accumulation slab
    __shared__ int offs[TT * 129];            // block's CSR bounds (slabs 0..5)
    __shared__ float inv[BM];                 // per-row 1/cnt for current slab

    int tid = threadIdx.x;
    int lane = tid & 63, wave = tid >> 6;
    int q = lane >> 4, c16 = lane & 15;
    int qid = tid >> 4, l16 = tid & 15;       // 16 quarters x 16 lanes
    int blockRow = blockIdx.x * BM;

    // preload CSR bounds: slab t covers off[t*N + blockRow .. +128]
    for (int i = tid; i < TT * 129; i += 256) {
        int t = i / 129, r = i - t * 129;
        int g = blockRow + r; if (g > N) g = N;
        offs[i] = off[t * N + g];
    }

    f32x4 acc[2][8];
#pragma unroll
    for (int rt = 0; rt < 2; ++rt)
#pragma unroll
        for (int ct = 0; ct < 8; ++ct) acc[rt][ct] = (f32x4){0.f, 0.f, 0.f, 0.f};

    int m0 = wave * 32 + c16;

#pragma unroll 1
    for (int t = 0; t < TT; ++t) {
        __syncthreads();   // previous MFMA done reading Asf; offs ready on t=0

        // zero A slab (128 cols per row) + per-row inv count
        for (int i = tid; i < BM * 64; i += 256) {
            int row = i >> 6, c2 = i & 63;
            *(float2*)&Asf[row * APITCH + c2 * 2] = make_float2(0.f, 0.f);
        }
        if (tid < BM) {
            int cn = offs[t * 129 + tid + 1] - offs[t * 129 + tid];
            inv[tid] = cn > 0 ? 1.f / (float)cn : 0.f;
        }
        __syncthreads();

        // edge-parallel accumulate: quarter qid takes a contiguous chunk
        int lo = offs[t * 129], hi = offs[t * 129 + BM];
        int cntE = hi - lo;
        int chunk = (cntE + 15) >> 4;
        int e0 = lo + qid * chunk;
        int e1 = e0 + chunk; if (e1 > hi) e1 = hi;
        int e = e0;
        for (; e + 4 <= e1; e += 4) {
            int p[4]; uint4 v[4]; float sc[4]; int rw[4];
#pragma unroll
            for (int j = 0; j < 4; ++j) p[j] = spk[e + j];
#pragma unroll
            for (int j = 0; j < 4; ++j) {
                int src = p[j] & 0x1ffff;
                rw[j] = p[j] >> 17;
                v[j] = *(const uint4*)(xb + (size_t)src * D + l16 * 8);
            }
#pragma unroll
            for (int j = 0; j < 4; ++j) sc[j] = inv[rw[j]];
#pragma unroll
            for (int j = 0; j < 4; ++j) {
                float* base = &Asf[rw[j] * APITCH + l16 * 8];
                atomicAdd(base + 0, bflo(v[j].x) * sc[j]);
                atomicAdd(base + 1, bfhi(v[j].x) * sc[j]);
                atomicAdd(base + 2, bflo(v[j].y) * sc[j]);
                atomicAdd(base + 3, bfhi(v[j].y) * sc[j]);
                atomicAdd(base + 4, bflo(v[j].z) * sc[j]);
                atomicAdd(base + 5, bfhi(v[j].z) * sc[j]);
                atomicAdd(base + 6, bflo(v[j].w) * sc[j]);
                atomicAdd(base + 7, bfhi(v[j].w) * sc[j]);
            }
        }
        for (; e < e1; ++e) {
            int p = spk[e];
            int src = p & 0x1ffff, row = p >> 17;
            uint4 v = *(const uint4*)(xb + (size_t)src * D + l16 * 8);
            float sc = inv[row];
            float* base = &Asf[row * APITCH + l16 * 8];
            atomicAdd(base + 0, bflo(v.x) * sc);
            atomicAdd(base + 1, bfhi(v.x) * sc);
            atomicAdd(base + 2, bflo(v.y) * sc);
            atomicAdd(base + 3, bfhi(v.y) * sc);
            atomicAdd(base + 4, bflo(v.z) * sc);
            atomicAdd(base + 5, bfhi(v.z) * sc);
            atomicAdd(base + 6, bflo(v.w) * sc);
            atomicAdd(base + 7, bfhi(v.w) * sc);
        }
        __syncthreads();

        // MFMA slab t: A from fp32 LDS (pack->bf16), B direct from global (L2-hot)
        uint4 bcur[8];
#pragma unroll
        for (int ct = 0; ct < 8; ++ct)
            bcur[ct] = *(const uint4*)(WlT + (size_t)(ct * 16 + c16) * KTOT + t * D + q * 8);
#pragma unroll
        for (int ks = 0; ks < 4; ++ks) {
            int kgrp = ks * 4 + q;
            uint4 bnxt[8];
            if (ks < 3) {
#pragma unroll
                for (int ct = 0; ct < 8; ++ct)
                    bnxt[ct] = *(const uint4*)(WlT + (size_t)(ct * 16 + c16) * KTOT + t * D + (kgrp + 4) * 8);
            }
            f32x4 x0 = *(const f32x4*)&Asf[m0 * APITCH + kgrp * 8];
            f32x4 x1 = *(const f32x4*)&Asf[m0 * APITCH + kgrp * 8 + 4];
            f32x4 y0 = *(const f32x4*)&Asf[(m0 + 16) * APITCH + kgrp * 8];
            f32x4 y1 = *(const f32x4*)&Asf[(m0 + 16) * APITCH + kgrp * 8 + 4];
            uint4 pa, pb;
            pa.x = pkbf(x0[0], x0[1]); pa.y = pkbf(x0[2], x0[3]);
            pa.z = pkbf(x1[0], x1[1]); pa.w = pkbf(x1[2], x1[3]);
            pb.x = pkbf(y0[0], y0[1]); pb.y = pkbf(y0[2], y0[3]);
            pb.z = pkbf(y1[0], y1[1]); pb.w = pkbf(y1[2], y1[3]);
            bf16x8 af0 = *(bf16x8*)&pa;
            bf16x8 af1 = *(bf16x8*)&pb;
#pragma unroll
            for (int ct = 0; ct < 8; ++ct) {
                bf16x8 bfr = *(bf16x8*)&bcur[ct];
                acc[0][ct] = __builtin_amdgcn_mfma_f32_16x16x32_bf16(af0, bfr, acc[0][ct], 0, 0, 0);
                acc[1][ct] = __builtin_amdgcn_mfma_f32_16x16x32_bf16(af1, bfr, acc[1][ct], 0, 0, 0);
            }
            if (ks < 3) {
#pragma unroll
                for (int ct = 0; ct < 8; ++ct) bcur[ct] = bnxt[ct];
            }
        }
    }

    // slab 6 (x @ sum W_r): A-frags straight from global xb, B from global
    {
        int rA = blockRow + m0;      if (rA >= N) rA = N - 1;
        int rB = blockRow + m0 + 16; if (rB >= N) rB = N - 1;
#pragma unroll
        for (int ks = 0; ks < 4; ++ks) {
            int kgrp = ks * 4 + q;
            bf16x8 af0 = *(const bf16x8*)(xb + (size_t)rA * D + kgrp * 8);
            bf16x8 af1 = *(const bf16x8*)(xb + (size_t)rB * D + kgrp * 8);
#pragma unroll
            for (int ct = 0; ct < 8; ++ct) {
                bf16x8 bfr = *(const bf16x8*)(WlT + (size_t)(ct * 16 + c16) * KTOT + TT * D + kgrp * 8);
                acc[0][ct] = __builtin_amdgcn_mfma_f32_16x16x32_bf16(af0, bfr, acc[0][ct], 0, 0, 0);
                acc[1][ct] = __builtin_amdgcn_mfma_f32_16x16x32_bf16(af1, bfr, acc[1][ct], 0, 0, 0);
            }
        }
    }

    // epilogue: bias + LayerNorm + ReLU
    float bias_c[8], g_c[8], bt_c[8];
#pragma unroll
    for (int ct = 0; ct < 8; ++ct) {
        int col = ct * 16 + c16;
        bias_c[ct] = bias_total[col];
        g_c[ct] = gamma[col];
        bt_c[ct] = beta[col];
    }
#pragma unroll
    for (int rt = 0; rt < 2; ++rt) {
#pragma unroll
        for (int reg = 0; reg < 4; ++reg) {
            float h[8];
            float s = 0.f, s2 = 0.f;
#pragma unroll
            for (int ct = 0; ct < 8; ++ct) {
                h[ct] = acc[rt][ct][reg] + bias_c[ct];
                s += h[ct];
                s2 += h[ct] * h[ct];
            }
#pragma unroll
            for (int o = 8; o >= 1; o >>= 1) {
                s  += __shfl_xor(s, o, 16);
                s2 += __shfl_xor(s2, o, 16);
            }
            float mu = s * (1.f / 128.f);
            float var = s2 * (1.f / 128.f) - mu * mu;
            float rstd = rsqrtf(var + LN_EPS);
            int row = blockRow + wave * 32 + rt * 16 + q * 4 + reg;
            if (row < N) {
#pragma unroll
                for (int ct = 0; ct < 8; ++ct) {
                    float y = (h[ct] - mu) * rstd * g_c[ct] + bt_c[ct];
                    out[(size_t)row * D + ct * 16 + c16] = fmaxf(y, 0.f);
                }
            }
        }
    }
}

extern "C" void kernel_launch(void* const* d_in, const int* in_sizes, int n_in,
                              void* d_out, int out_size, void* d_ws, size_t ws_size,
                              hipStream_t stream) {
    const float* x     = (const float*)d_in[0];
    const int*   ei    = (const int*)d_in[1];
    const int*   et    = (const int*)d_in[2];
    const float* W_l   = (const float*)d_in[3];
    const float* W_r   = (const float*)d_in[4];
    const float* b     = (const float*)d_in[5];
    const float* emb   = (const float*)d_in[6];
    const float* gamma = (const float*)d_in[7];
    const float* beta  = (const float*)d_in[8];

    int N = in_sizes[0] / D;
    int E = in_sizes[2];
    int S = N * TT;
    int NB = (S + SCAN_BLK - 1) / SCAN_BLK;
    int NBLK = (N + BM - 1) / BM;

    // workspace carve
    int* hist       = (int*)d_ws;            // S
    int* off        = hist + S;              // S+1
    int* cursor     = off + S + 1;           // S
    int* agg        = cursor + S;            // NB
    int* flag       = agg + NB;              // NB
    int* spk        = flag + NB;             // E (packed src|row)
    size_t ofs = (size_t)((char*)(spk + E) - (char*)d_ws);
    ofs = (ofs + 15) & ~(size_t)15;
    unsigned short* WlT = (unsigned short*)((char*)d_ws + ofs);   // 128*896
    float* bias_total = (float*)(WlT + D * KTOT);                 // 128
    size_t ofs2 = (size_t)((char*)(bias_total + D) - (char*)d_ws);
    ofs2 = (ofs2 + 15) & ~(size_t)15;
    unsigned short* xb = (unsigned short*)((char*)d_ws + ofs2);   // N*128 bf16

    int total8 = N * D / 8;
    int G = total8 + 7 * D * D + D + S + NB;
    setup_kernel<<<(G + 255) / 256, 256, 0, stream>>>(x, W_l, W_r, b, emb, xb, WlT,
                                                      bias_total, hist, flag, total8, S, NB);

    hist_kernel<<<(E + 255) / 256, 256, 0, stream>>>(ei, et, hist, E, N);
    scan_kernel<<<NB, 256, 0, stream>>>(hist, off, cursor, agg, flag, S, E);
    fill_kernel<<<(E + 255) / 256, 256, 0, stream>>>(ei, et, cursor, spk, E, N);

    fused_kernel<<<NBLK, 256, 0, stream>>>(xb, off, spk, WlT, bias_total,
                                           gamma, beta, (float*)d_out, N);
}

// Round 9
// 299.880 us; speedup vs baseline: 2.4482x; 2.4482x over previous
//
#include <hip/hip_runtime.h>

#define TT 6
#define D 128
#define KTOT 896           // 6*128 means + 128 x-slab
#define BM 64
#define SCAN_BLK 2048
#define LN_EPS 1e-5f

typedef __bf16 bf16x8 __attribute__((ext_vector_type(8)));
typedef float f32x4 __attribute__((ext_vector_type(4)));

__device__ __forceinline__ unsigned short f2bf(float f) {
    unsigned int u = __float_as_uint(f);
    unsigned int r = (u + 0x7FFFu + ((u >> 16) & 1u)) >> 16;  // RNE
    return (unsigned short)r;
}
__device__ __forceinline__ float bflo(unsigned int v) { return __uint_as_float(v << 16); }
__device__ __forceinline__ float bfhi(unsigned int v) { return __uint_as_float(v & 0xffff0000u); }

// XOR-swizzled LDS offset (ushort elems) for 128-elem rows: 16 chunks of 8.
__device__ __forceinline__ int lds_off128(int row, int kgrp) {
    return row * 128 + (((kgrp & 7) ^ (row & 7)) | (kgrp & 8)) * 8;
}

// --- setup: cast x->xb, transpose weights to bf16 WlT, bias_total, hist atomics ---
__global__ void setup_kernel(const float* __restrict__ x, const float* __restrict__ W_l,
                             const float* __restrict__ W_r, const float* __restrict__ b,
                             const float* __restrict__ emb,
                             const int* __restrict__ ei, const int* __restrict__ et,
                             unsigned short* __restrict__ xb, unsigned short* __restrict__ WlT,
                             float* __restrict__ bias_total, int* __restrict__ hist,
                             int total8, int E, int N) {
    int i = blockIdx.x * 256 + threadIdx.x;
    if (i < total8) {
        const float4* p = (const float4*)x + (size_t)i * 2;
        float4 a = p[0], bb = p[1];
        uint4 o;
        o.x = (unsigned int)f2bf(a.x) | ((unsigned int)f2bf(a.y) << 16);
        o.y = (unsigned int)f2bf(a.z) | ((unsigned int)f2bf(a.w) << 16);
        o.z = (unsigned int)f2bf(bb.x) | ((unsigned int)f2bf(bb.y) << 16);
        o.w = (unsigned int)f2bf(bb.z) | ((unsigned int)f2bf(bb.w) << 16);
        ((uint4*)xb)[i] = o;
        return;
    }
    i -= total8;
    if (i < 6 * D * D) {
        int t = i >> 14, rem = i & 16383, k = rem >> 7, n = rem & 127;
        WlT[n * KTOT + t * D + k] = f2bf(W_l[i]);
        return;
    }
    if (i < 7 * D * D) {
        int rem = i & 16383, k = rem >> 7, n = rem & 127;
        float s = 0.f;
#pragma unroll
        for (int tt = 0; tt < TT; ++tt) s += W_r[tt * D * D + rem];
        WlT[n * KTOT + TT * D + k] = f2bf(s);
        return;
    }
    if (i < 7 * D * D + D) {
        int o = i - 7 * D * D;
        float s = 0.f;
#pragma unroll
        for (int t = 0; t < TT; ++t) s += b[t * D + o] + emb[t * D + o];
        bias_total[o] = s;
        return;
    }
    i -= 7 * D * D + D;
    if (i < E) {
        atomicAdd(&hist[et[i] * N + ei[E + i]], 1);
    }
}

// --- single-dispatch exclusive scan (decoupled lookback, all-aggregate form) ---
__global__ void scan_kernel(const int* __restrict__ in, int* __restrict__ off,
                            int* __restrict__ cursor, int* __restrict__ agg,
                            int* __restrict__ flag, int S, int E) {
    __shared__ int wsum[4];
    __shared__ int woff[4];
    __shared__ int psum[4];
    __shared__ int s_prefix;
    int tid = threadIdx.x;
    int tile = blockIdx.x;
    int base = tile * SCAN_BLK + tid * 8;
    int v[8];
    int ts = 0;
#pragma unroll
    for (int j = 0; j < 8; ++j) {
        v[j] = (base + j < S) ? in[base + j] : 0;
        ts += v[j];
    }
    int lane = tid & 63, wave = tid >> 6;
    int inc = ts;
#pragma unroll
    for (int o = 1; o < 64; o <<= 1) {
        int n = __shfl_up(inc, o);
        if (lane >= o) inc += n;
    }
    if (lane == 63) wsum[wave] = inc;
    __syncthreads();
    if (tid == 0) {
        int r = 0;
#pragma unroll
        for (int w = 0; w < 4; ++w) { int t = wsum[w]; woff[w] = r; r += t; }
        agg[tile] = r;
        __threadfence();
        atomicExch(&flag[tile], 1);
    }
    int part = 0;
    for (int j = tid; j < tile; j += 256) {
        while (atomicAdd(&flag[j], 0) == 0) {}
        part += atomicAdd(&agg[j], 0);
    }
#pragma unroll
    for (int o = 32; o >= 1; o >>= 1) part += __shfl_down(part, o);
    if (lane == 0) psum[wave] = part;
    __syncthreads();
    if (tid == 0) s_prefix = psum[0] + psum[1] + psum[2] + psum[3];
    __syncthreads();
    int run = s_prefix + woff[wave] + inc - ts;
#pragma unroll
    for (int j = 0; j < 8; ++j) {
        if (base + j < S) { off[base + j] = run; cursor[base + j] = run; }
        run += v[j];
    }
    if (tile == 0 && tid == 0) off[S] = E;
}

__global__ void fill_kernel(const int* __restrict__ ei, const int* __restrict__ et,
                            int* __restrict__ cursor, int* __restrict__ sorted_src,
                            int E, int N) {
    int e = blockIdx.x * 256 + threadIdx.x;
    if (e >= E) return;
    int seg = et[e] * N + ei[E + e];
    int pos = atomicAdd(&cursor[seg], 1);
    sorted_src[pos] = ei[e];
}

// --- fused: prefetch-2 pipelined mean aggregation (BM=64 -> 782 blocks, 3/CU)
//     -> bf16 MFMA (B direct from L2-hot global) -> bias+LN+ReLU ---
__launch_bounds__(256, 3)
__global__ void fused_kernel(const unsigned short* __restrict__ xb,
                             const int* __restrict__ off, const int* __restrict__ sorted_src,
                             const unsigned short* __restrict__ WlT,
                             const float* __restrict__ bias_total,
                             const float* __restrict__ gamma, const float* __restrict__ beta,
                             float* __restrict__ out, int N) {
    __shared__ unsigned short As[BM * 128];   // 16 KB swizzled A slab [m][k]
    __shared__ int offs[TT * (BM + 1)];       // block's CSR bounds (slabs 0..5)

    int tid = threadIdx.x;
    int lane = tid & 63, wave = tid >> 6;
    int q = lane >> 4, c16 = lane & 15;
    int qid = tid >> 4, l16 = tid & 15;       // 16 quarters x 16 lanes
    int blockRow = blockIdx.x * BM;

    // preload CSR bounds: slab t covers off[t*N + blockRow .. +64]
    for (int i = tid; i < TT * (BM + 1); i += 256) {
        int t = i / (BM + 1), r = i - t * (BM + 1);
        int g = blockRow + r; if (g > N) g = N;
        offs[i] = off[t * N + g];
    }

    f32x4 acc[8];
#pragma unroll
    for (int ct = 0; ct < 8; ++ct) acc[ct] = (f32x4){0.f, 0.f, 0.f, 0.f};

    int m0 = wave * 16 + c16;   // this lane's A row (block-local)

    __syncthreads();   // offs ready

#pragma unroll 1
    for (int t = 0; t < TT; ++t) {
        if (t > 0) __syncthreads();   // previous MFMA frag reads complete

        // ---- aggregation: 4 rows per quarter, prefetch-2 pipeline ----
        {
            int rowbase = qid * 4;
            int e0[4], cn[4];
#pragma unroll
            for (int i = 0; i < 4; ++i) {
                int row = rowbase + i;
                int a = offs[t * (BM + 1) + row];
                int bnd = offs[t * (BM + 1) + row + 1];
                e0[i] = a;
                cn[i] = (blockRow + row < N) ? (bnd - a) : 0;
            }
            int i0[4], i1[4];
#pragma unroll
            for (int i = 0; i < 4; ++i) {
                i0[i] = 0; i1[i] = 0;
                if (cn[i] > 0) i0[i] = sorted_src[e0[i]];
                if (cn[i] > 1) i1[i] = sorted_src[e0[i] + 1];
            }
            uint4 v0[4], v1[4];
#pragma unroll
            for (int i = 0; i < 4; ++i) {
                v0[i] = (uint4){0u, 0u, 0u, 0u};
                if (cn[i] > 0) v0[i] = *(const uint4*)(xb + (size_t)i0[i] * D + l16 * 8);
            }
#pragma unroll
            for (int i = 0; i < 4; ++i) {
                v1[i] = (uint4){0u, 0u, 0u, 0u};
                if (cn[i] > 1) v1[i] = *(const uint4*)(xb + (size_t)i1[i] * D + l16 * 8);
            }
#pragma unroll
            for (int i = 0; i < 4; ++i) {
                float a0 = bflo(v0[i].x) + bflo(v1[i].x);
                float a1 = bfhi(v0[i].x) + bfhi(v1[i].x);
                float a2 = bflo(v0[i].y) + bflo(v1[i].y);
                float a3 = bfhi(v0[i].y) + bfhi(v1[i].y);
                float a4 = bflo(v0[i].z) + bflo(v1[i].z);
                float a5 = bfhi(v0[i].z) + bfhi(v1[i].z);
                float a6 = bflo(v0[i].w) + bflo(v1[i].w);
                float a7 = bfhi(v0[i].w) + bfhi(v1[i].w);
                int e = e0[i] + 2, end = e0[i] + cn[i];
#pragma unroll 1
                while (e < end) {
                    int s = sorted_src[e++];
                    uint4 v = *(const uint4*)(xb + (size_t)s * D + l16 * 8);
                    a0 += bflo(v.x); a1 += bfhi(v.x);
                    a2 += bflo(v.y); a3 += bfhi(v.y);
                    a4 += bflo(v.z); a5 += bfhi(v.z);
                    a6 += bflo(v.w); a7 += bfhi(v.w);
                }
                if (cn[i] > 1) {
                    float sc = 1.f / (float)cn[i];
                    a0 *= sc; a1 *= sc; a2 *= sc; a3 *= sc;
                    a4 *= sc; a5 *= sc; a6 *= sc; a7 *= sc;
                }
                uint4 p;
                p.x = (unsigned int)f2bf(a0) | ((unsigned int)f2bf(a1) << 16);
                p.y = (unsigned int)f2bf(a2) | ((unsigned int)f2bf(a3) << 16);
                p.z = (unsigned int)f2bf(a4) | ((unsigned int)f2bf(a5) << 16);
                p.w = (unsigned int)f2bf(a6) | ((unsigned int)f2bf(a7) << 16);
                *(uint4*)&As[lds_off128(rowbase + i, l16)] = p;
            }
        }
        __syncthreads();

        // ---- MFMA slab t: A frags from LDS, B frags direct from global (L2-hot) ----
        uint4 bcur[8];
#pragma unroll
        for (int ct = 0; ct < 8; ++ct)
            bcur[ct] = *(const uint4*)(WlT + (size_t)(ct * 16 + c16) * KTOT + t * D + q * 8);
#pragma unroll
        for (int ks = 0; ks < 4; ++ks) {
            int kgrp = ks * 4 + q;
            uint4 bnxt[8];
            if (ks < 3) {
#pragma unroll
                for (int ct = 0; ct < 8; ++ct)
                    bnxt[ct] = *(const uint4*)(WlT + (size_t)(ct * 16 + c16) * KTOT + t * D + (kgrp + 4) * 8);
            }
            bf16x8 af = *(const bf16x8*)&As[lds_off128(m0, kgrp)];
#pragma unroll
            for (int ct = 0; ct < 8; ++ct) {
                bf16x8 bfr = *(bf16x8*)&bcur[ct];
                acc[ct] = __builtin_amdgcn_mfma_f32_16x16x32_bf16(af, bfr, acc[ct], 0, 0, 0);
            }
            if (ks < 3) {
#pragma unroll
                for (int ct = 0; ct < 8; ++ct) bcur[ct] = bnxt[ct];
            }
        }
    }

    // ---- slab 6 (x @ sum W_r): A frags direct from xb, B direct from global ----
    {
        int rA = blockRow + m0; if (rA >= N) rA = N - 1;
#pragma unroll
        for (int ks = 0; ks < 4; ++ks) {
            int kgrp = ks * 4 + q;
            bf16x8 af = *(const bf16x8*)(xb + (size_t)rA * D + kgrp * 8);
#pragma unroll
            for (int ct = 0; ct < 8; ++ct) {
                bf16x8 bfr = *(const bf16x8*)(WlT + (size_t)(ct * 16 + c16) * KTOT + TT * D + kgrp * 8);
                acc[ct] = __builtin_amdgcn_mfma_f32_16x16x32_bf16(af, bfr, acc[ct], 0, 0, 0);
            }
        }
    }

    // ---- epilogue: bias + LayerNorm + ReLU ----
    float bias_c[8], g_c[8], bt_c[8];
#pragma unroll
    for (int ct = 0; ct < 8; ++ct) {
        int col = ct * 16 + c16;
        bias_c[ct] = bias_total[col];
        g_c[ct] = gamma[col];
        bt_c[ct] = beta[col];
    }
#pragma unroll
    for (int reg = 0; reg < 4; ++reg) {
        float h[8];
        float s = 0.f, s2 = 0.f;
#pragma unroll
        for (int ct = 0; ct < 8; ++ct) {
            h[ct] = acc[ct][reg] + bias_c[ct];
            s += h[ct];
            s2 += h[ct] * h[ct];
        }
#pragma unroll
        for (int o = 8; o >= 1; o >>= 1) {
            s  += __shfl_xor(s, o, 16);
            s2 += __shfl_xor(s2, o, 16);
        }
        float mu = s * (1.f / 128.f);
        float var = s2 * (1.f / 128.f) - mu * mu;
        float rstd = rsqrtf(var + LN_EPS);
        int row = blockRow + wave * 16 + q * 4 + reg;
        if (row < N) {
#pragma unroll
            for (int ct = 0; ct < 8; ++ct) {
                float y = (h[ct] - mu) * rstd * g_c[ct] + bt_c[ct];
                out[(size_t)row * D + ct * 16 + c16] = fmaxf(y, 0.f);
            }
        }
    }
}

extern "C" void kernel_launch(void* const* d_in, const int* in_sizes, int n_in,
                              void* d_out, int out_size, void* d_ws, size_t ws_size,
                              hipStream_t stream) {
    const float* x     = (const float*)d_in[0];
    const int*   ei    = (const int*)d_in[1];
    const int*   et    = (const int*)d_in[2];
    const float* W_l   = (const float*)d_in[3];
    const float* W_r   = (const float*)d_in[4];
    const float* b     = (const float*)d_in[5];
    const float* emb   = (const float*)d_in[6];
    const float* gamma = (const float*)d_in[7];
    const float* beta  = (const float*)d_in[8];

    int N = in_sizes[0] / D;
    int E = in_sizes[2];
    int S = N * TT;
    int NB = (S + SCAN_BLK - 1) / SCAN_BLK;
    int NBLK = (N + BM - 1) / BM;

    // workspace carve (hist & flag contiguous -> one memset)
    int* hist       = (int*)d_ws;            // S
    int* flag       = hist + S;              // NB
    int* off        = flag + NB;             // S+1
    int* cursor     = off + S + 1;           // S
    int* agg        = cursor + S;            // NB
    int* sorted_src = agg + NB;              // E
    size_t ofs = (size_t)((char*)(sorted_src + E) - (char*)d_ws);
    ofs = (ofs + 15) & ~(size_t)15;
    unsigned short* WlT = (unsigned short*)((char*)d_ws + ofs);   // 128*896
    float* bias_total = (float*)(WlT + D * KTOT);                 // 128
    size_t ofs2 = (size_t)((char*)(bias_total + D) - (char*)d_ws);
    ofs2 = (ofs2 + 15) & ~(size_t)15;
    unsigned short* xb = (unsigned short*)((char*)d_ws + ofs2);   // N*128 bf16

    hipMemsetAsync(hist, 0, (size_t)(S + NB) * sizeof(int), stream);

    int total8 = N * D / 8;
    int G = total8 + 7 * D * D + D + E;
    setup_kernel<<<(G + 255) / 256, 256, 0, stream>>>(x, W_l, W_r, b, emb, ei, et,
                                                      xb, WlT, bias_total, hist,
                                                      total8, E, N);

    scan_kernel<<<NB, 256, 0, stream>>>(hist, off, cursor, agg, flag, S, E);
    fill_kernel<<<(E + 255) / 256, 256, 0, stream>>>(ei, et, cursor, sorted_src, E, N);

    fused_kernel<<<NBLK, 256, 0, stream>>>(xb, off, sorted_src, WlT, bias_total,
                                           gamma, beta, (float*)d_out, N);
}

// Round 10
// 293.261 us; speedup vs baseline: 2.5035x; 1.0226x over previous
//
#include <hip/hip_runtime.h>

#define TT 6
#define D 128
#define KTOT 896           // 6*128 means + 128 x-slab
#define BM 64
#define SCAN_BLK 2048
#define LN_EPS 1e-5f

typedef __bf16 bf16x8 __attribute__((ext_vector_type(8)));
typedef float f32x4 __attribute__((ext_vector_type(4)));

__device__ __forceinline__ unsigned short f2bf(float f) {
    unsigned int u = __float_as_uint(f);
    unsigned int r = (u + 0x7FFFu + ((u >> 16) & 1u)) >> 16;  // RNE
    return (unsigned short)r;
}
__device__ __forceinline__ float bflo(unsigned int v) { return __uint_as_float(v << 16); }
__device__ __forceinline__ float bfhi(unsigned int v) { return __uint_as_float(v & 0xffff0000u); }
// pack 2 fp32 -> bf16 pair (round-half-up; validated R8)
__device__ __forceinline__ unsigned int pkbf(float f0, float f1) {
    unsigned int u0 = (__float_as_uint(f0) + 0x8000u) >> 16;
    unsigned int u1 = (__float_as_uint(f1) + 0x8000u) & 0xffff0000u;
    return u0 | u1;
}

// --- setup: cast x->xb, transpose weights to bf16 WlT, bias_total, hist atomics ---
__global__ void setup_kernel(const float* __restrict__ x, const float* __restrict__ W_l,
                             const float* __restrict__ W_r, const float* __restrict__ b,
                             const float* __restrict__ emb,
                             const int* __restrict__ ei, const int* __restrict__ et,
                             unsigned short* __restrict__ xb, unsigned short* __restrict__ WlT,
                             float* __restrict__ bias_total, int* __restrict__ hist,
                             int total8, int E, int N) {
    int i = blockIdx.x * 256 + threadIdx.x;
    if (i < total8) {
        const float4* p = (const float4*)x + (size_t)i * 2;
        float4 a = p[0], bb = p[1];
        uint4 o;
        o.x = (unsigned int)f2bf(a.x) | ((unsigned int)f2bf(a.y) << 16);
        o.y = (unsigned int)f2bf(a.z) | ((unsigned int)f2bf(a.w) << 16);
        o.z = (unsigned int)f2bf(bb.x) | ((unsigned int)f2bf(bb.y) << 16);
        o.w = (unsigned int)f2bf(bb.z) | ((unsigned int)f2bf(bb.w) << 16);
        ((uint4*)xb)[i] = o;
        return;
    }
    i -= total8;
    if (i < 6 * D * D) {
        int t = i >> 14, rem = i & 16383, k = rem >> 7, n = rem & 127;
        WlT[n * KTOT + t * D + k] = f2bf(W_l[i]);
        return;
    }
    if (i < 7 * D * D) {
        int rem = i & 16383, k = rem >> 7, n = rem & 127;
        float s = 0.f;
#pragma unroll
        for (int tt = 0; tt < TT; ++tt) s += W_r[tt * D * D + rem];
        WlT[n * KTOT + TT * D + k] = f2bf(s);
        return;
    }
    if (i < 7 * D * D + D) {
        int o = i - 7 * D * D;
        float s = 0.f;
#pragma unroll
        for (int t = 0; t < TT; ++t) s += b[t * D + o] + emb[t * D + o];
        bias_total[o] = s;
        return;
    }
    i -= 7 * D * D + D;
    if (i < E) {
        atomicAdd(&hist[et[i] * N + ei[E + i]], 1);
    }
}

// --- single-dispatch exclusive scan (decoupled lookback, all-aggregate form) ---
__global__ void scan_kernel(const int* __restrict__ in, int* __restrict__ off,
                            int* __restrict__ cursor, int* __restrict__ agg,
                            int* __restrict__ flag, int S, int E) {
    __shared__ int wsum[4];
    __shared__ int woff[4];
    __shared__ int psum[4];
    __shared__ int s_prefix;
    int tid = threadIdx.x;
    int tile = blockIdx.x;
    int base = tile * SCAN_BLK + tid * 8;
    int v[8];
    int ts = 0;
#pragma unroll
    for (int j = 0; j < 8; ++j) {
        v[j] = (base + j < S) ? in[base + j] : 0;
        ts += v[j];
    }
    int lane = tid & 63, wave = tid >> 6;
    int inc = ts;
#pragma unroll
    for (int o = 1; o < 64; o <<= 1) {
        int n = __shfl_up(inc, o);
        if (lane >= o) inc += n;
    }
    if (lane == 63) wsum[wave] = inc;
    __syncthreads();
    if (tid == 0) {
        int r = 0;
#pragma unroll
        for (int w = 0; w < 4; ++w) { int t = wsum[w]; woff[w] = r; r += t; }
        agg[tile] = r;
        __threadfence();
        atomicExch(&flag[tile], 1);
    }
    int part = 0;
    for (int j = tid; j < tile; j += 256) {
        while (atomicAdd(&flag[j], 0) == 0) {}
        part += atomicAdd(&agg[j], 0);
    }
#pragma unroll
    for (int o = 32; o >= 1; o >>= 1) part += __shfl_down(part, o);
    if (lane == 0) psum[wave] = part;
    __syncthreads();
    if (tid == 0) s_prefix = psum[0] + psum[1] + psum[2] + psum[3];
    __syncthreads();
    int run = s_prefix + woff[wave] + inc - ts;
#pragma unroll
    for (int j = 0; j < 8; ++j) {
        if (base + j < S) { off[base + j] = run; cursor[base + j] = run; }
        run += v[j];
    }
    if (tile == 0 && tid == 0) off[S] = E;
}

__global__ void fill_kernel(const int* __restrict__ ei, const int* __restrict__ et,
                            int* __restrict__ cursor, int* __restrict__ sorted_src,
                            int E, int N) {
    int e = blockIdx.x * 256 + threadIdx.x;
    if (e >= E) return;
    int seg = et[e] * N + ei[E + e];
    int pos = atomicAdd(&cursor[seg], 1);
    sorted_src[pos] = ei[e];
}

// --- fused: barrier-free register-direct aggregation -> bf16 MFMA -> bias+LN+ReLU.
//     Lane (qd=lane>>4, r=lane&15) owns row wave*16+r restricted to k-chunks
//     {qd,qd+4,qd+8,qd+12}; its 32 accumulated floats ARE the 4 A-frags (ks=0..3).
//     No LDS, no __syncthreads in the main loop; waves drift independently.
__launch_bounds__(256, 3)
__global__ void fused_kernel(const unsigned short* __restrict__ xb,
                             const int* __restrict__ off, const int* __restrict__ sorted_src,
                             const unsigned short* __restrict__ WlT,
                             const float* __restrict__ bias_total,
                             const float* __restrict__ gamma, const float* __restrict__ beta,
                             float* __restrict__ out, int N) {
    int tid = threadIdx.x;
    int lane = tid & 63, wave = tid >> 6;
    int qd = lane >> 4, r = lane & 15;
    int blockRow = blockIdx.x * BM;
    int myRow = blockRow + wave * 16 + r;
    bool rowValid = myRow < N;

    f32x4 acc[8];
#pragma unroll
    for (int ct = 0; ct < 8; ++ct) acc[ct] = (f32x4){0.f, 0.f, 0.f, 0.f};

#pragma unroll 1
    for (int t = 0; t < TT; ++t) {
        // CSR bounds (L2-hot; 4 qd-lanes broadcast-load same address)
        int e0 = 0, cnt = 0;
        if (rowValid) {
            int seg = t * N + myRow;
            e0 = off[seg];
            cnt = off[seg + 1] - e0;
        }

        float ar[4][8];
#pragma unroll
        for (int j = 0; j < 4; ++j)
#pragma unroll
            for (int k = 0; k < 8; ++k) ar[j][k] = 0.f;

        // prefetch-2: first two edges' indices, then all 8 gathers in flight
        int iA = 0, iB = 0;
        if (cnt > 0) iA = sorted_src[e0];
        if (cnt > 1) iB = sorted_src[e0 + 1];
        uint4 va[4], vb[4];
#pragma unroll
        for (int j = 0; j < 4; ++j) { va[j] = (uint4){0,0,0,0}; vb[j] = (uint4){0,0,0,0}; }
        if (cnt > 0) {
#pragma unroll
            for (int j = 0; j < 4; ++j)
                va[j] = *(const uint4*)(xb + (size_t)iA * D + (qd + 4 * j) * 8);
        }
        if (cnt > 1) {
#pragma unroll
            for (int j = 0; j < 4; ++j)
                vb[j] = *(const uint4*)(xb + (size_t)iB * D + (qd + 4 * j) * 8);
        }
#pragma unroll
        for (int j = 0; j < 4; ++j) {
            ar[j][0] += bflo(va[j].x) + bflo(vb[j].x);
            ar[j][1] += bfhi(va[j].x) + bfhi(vb[j].x);
            ar[j][2] += bflo(va[j].y) + bflo(vb[j].y);
            ar[j][3] += bfhi(va[j].y) + bfhi(vb[j].y);
            ar[j][4] += bflo(va[j].z) + bflo(vb[j].z);
            ar[j][5] += bfhi(va[j].z) + bfhi(vb[j].z);
            ar[j][6] += bflo(va[j].w) + bflo(vb[j].w);
            ar[j][7] += bfhi(va[j].w) + bfhi(vb[j].w);
        }
        // tail (divergent-max over the wave's 16 rows; each iter = 4 indep loads)
#pragma unroll 1
        for (int e = e0 + 2; e < e0 + cnt; ++e) {
            int idx = sorted_src[e];
            uint4 v[4];
#pragma unroll
            for (int j = 0; j < 4; ++j)
                v[j] = *(const uint4*)(xb + (size_t)idx * D + (qd + 4 * j) * 8);
#pragma unroll
            for (int j = 0; j < 4; ++j) {
                ar[j][0] += bflo(v[j].x); ar[j][1] += bfhi(v[j].x);
                ar[j][2] += bflo(v[j].y); ar[j][3] += bfhi(v[j].y);
                ar[j][4] += bflo(v[j].z); ar[j][5] += bfhi(v[j].z);
                ar[j][6] += bflo(v[j].w); ar[j][7] += bfhi(v[j].w);
            }
        }
        if (cnt > 1) {
            float sc = 1.f / (float)cnt;
#pragma unroll
            for (int j = 0; j < 4; ++j)
#pragma unroll
                for (int k = 0; k < 8; ++k) ar[j][k] *= sc;
        }
        // pack: chunk j is exactly the A-frag for ks=j
        uint4 afr[4];
#pragma unroll
        for (int j = 0; j < 4; ++j) {
            afr[j].x = pkbf(ar[j][0], ar[j][1]);
            afr[j].y = pkbf(ar[j][2], ar[j][3]);
            afr[j].z = pkbf(ar[j][4], ar[j][5]);
            afr[j].w = pkbf(ar[j][6], ar[j][7]);
        }

        // MFMA slab t: A from registers, B direct from global (L2-hot)
#pragma unroll
        for (int ks = 0; ks < 4; ++ks) {
            bf16x8 af = *(bf16x8*)&afr[ks];
#pragma unroll
            for (int ct = 0; ct < 8; ++ct) {
                bf16x8 bfr = *(const bf16x8*)(WlT + (size_t)(ct * 16 + r) * KTOT + t * D + (ks * 4 + qd) * 8);
                acc[ct] = __builtin_amdgcn_mfma_f32_16x16x32_bf16(af, bfr, acc[ct], 0, 0, 0);
            }
        }
    }

    // slab 6 (x @ sum W_r): A frags direct from xb
    {
        int rA = rowValid ? myRow : N - 1;
#pragma unroll
        for (int ks = 0; ks < 4; ++ks) {
            bf16x8 af = *(const bf16x8*)(xb + (size_t)rA * D + (ks * 4 + qd) * 8);
#pragma unroll
            for (int ct = 0; ct < 8; ++ct) {
                bf16x8 bfr = *(const bf16x8*)(WlT + (size_t)(ct * 16 + r) * KTOT + TT * D + (ks * 4 + qd) * 8);
                acc[ct] = __builtin_amdgcn_mfma_f32_16x16x32_bf16(af, bfr, acc[ct], 0, 0, 0);
            }
        }
    }

    // epilogue: bias + LayerNorm + ReLU   (C-layout: col = r, row = qd*4+reg)
    float bias_c[8], g_c[8], bt_c[8];
#pragma unroll
    for (int ct = 0; ct < 8; ++ct) {
        int col = ct * 16 + r;
        bias_c[ct] = bias_total[col];
        g_c[ct] = gamma[col];
        bt_c[ct] = beta[col];
    }
#pragma unroll
    for (int reg = 0; reg < 4; ++reg) {
        float h[8];
        float s = 0.f, s2 = 0.f;
#pragma unroll
        for (int ct = 0; ct < 8; ++ct) {
            h[ct] = acc[ct][reg] + bias_c[ct];
            s += h[ct];
            s2 += h[ct] * h[ct];
        }
#pragma unroll
        for (int o = 8; o >= 1; o >>= 1) {
            s  += __shfl_xor(s, o, 16);
            s2 += __shfl_xor(s2, o, 16);
        }
        float mu = s * (1.f / 128.f);
        float var = s2 * (1.f / 128.f) - mu * mu;
        float rstd = rsqrtf(var + LN_EPS);
        int row = blockRow + wave * 16 + qd * 4 + reg;
        if (row < N) {
#pragma unroll
            for (int ct = 0; ct < 8; ++ct) {
                float y = (h[ct] - mu) * rstd * g_c[ct] + bt_c[ct];
                out[(size_t)row * D + ct * 16 + r] = fmaxf(y, 0.f);
            }
        }
    }
}

extern "C" void kernel_launch(void* const* d_in, const int* in_sizes, int n_in,
                              void* d_out, int out_size, void* d_ws, size_t ws_size,
                              hipStream_t stream) {
    const float* x     = (const float*)d_in[0];
    const int*   ei    = (const int*)d_in[1];
    const int*   et    = (const int*)d_in[2];
    const float* W_l   = (const float*)d_in[3];
    const float* W_r   = (const float*)d_in[4];
    const float* b     = (const float*)d_in[5];
    const float* emb   = (const float*)d_in[6];
    const float* gamma = (const float*)d_in[7];
    const float* beta  = (const float*)d_in[8];

    int N = in_sizes[0] / D;
    int E = in_sizes[2];
    int S = N * TT;
    int NB = (S + SCAN_BLK - 1) / SCAN_BLK;
    int NBLK = (N + BM - 1) / BM;

    // workspace carve (hist & flag contiguous -> one memset)
    int* hist       = (int*)d_ws;            // S
    int* flag       = hist + S;              // NB
    int* off        = flag + NB;             // S+1
    int* cursor     = off + S + 1;           // S
    int* agg        = cursor + S;            // NB
    int* sorted_src = agg + NB;              // E
    size_t ofs = (size_t)((char*)(sorted_src + E) - (char*)d_ws);
    ofs = (ofs + 15) & ~(size_t)15;
    unsigned short* WlT = (unsigned short*)((char*)d_ws + ofs);   // 128*896
    float* bias_total = (float*)(WlT + D * KTOT);                 // 128
    size_t ofs2 = (size_t)((char*)(bias_total + D) - (char*)d_ws);
    ofs2 = (ofs2 + 15) & ~(size_t)15;
    unsigned short* xb = (unsigned short*)((char*)d_ws + ofs2);   // N*128 bf16

    hipMemsetAsync(hist, 0, (size_t)(S + NB) * sizeof(int), stream);

    int total8 = N * D / 8;
    int G = total8 + 7 * D * D + D + E;
    setup_kernel<<<(G + 255) / 256, 256, 0, stream>>>(x, W_l, W_r, b, emb, ei, et,
                                                      xb, WlT, bias_total, hist,
                                                      total8, E, N);

    scan_kernel<<<NB, 256, 0, stream>>>(hist, off, cursor, agg, flag, S, E);
    fill_kernel<<<(E + 255) / 256, 256, 0, stream>>>(ei, et, cursor, sorted_src, E, N);

    fused_kernel<<<NBLK, 256, 0, stream>>>(xb, off, sorted_src, WlT, bias_total,
                                           gamma, beta, (float*)d_out, N);
}